// Round 4
// baseline (1589.273 us; speedup 1.0000x reference)
//
#include <hip/hip_runtime.h>
#include <hip/hip_bf16.h>

#define BB 8
#define TT 2048
#define DD 256
#define KK 4
#define CSZ 1024
#define NROWS (BB*TT)   // 16384
#define TM 16           // rows per block -> 1024 blocks
#define TAU 0.05f

// monotone double -> u64 encoding (ascending order preserved)
__device__ __forceinline__ unsigned long long enc_d(double d) {
    unsigned long long u = __double_as_longlong(d);
    return (u & 0x8000000000000000ull) ? ~u : (u | 0x8000000000000000ull);
}

// cbT[k][d][c] = cb[k][c][d]
__global__ __launch_bounds__(256) void transpose_cb(const float* __restrict__ cb,
                                                    float* __restrict__ cbT) {
    long e = (long)blockIdx.x * 256 + threadIdx.x;   // over K*D*CS
    int k   = (int)(e / (DD * CSZ));
    int rem = (int)(e - (long)k * (DD * CSZ));
    int d   = rem / CSZ;
    int c   = rem - d * CSZ;
    cbT[e] = cb[(long)k * CSZ * DD + (long)c * DD + d];
}

// per-entry squared norms (fp64 master + fp32 for the scan)
__global__ __launch_bounds__(256) void cnorm_kernel(const float* __restrict__ cb,
                                                    double* __restrict__ cn_d,
                                                    float* __restrict__ cn_f) {
    int e = blockIdx.x * 256 + threadIdx.x;          // K*CS = 4096
    const float* p = cb + (long)e * DD;
    double s = 0.0;
    for (int d = 0; d < DD; ++d) { double v = (double)p[d]; s += v * v; }
    cn_d[e] = s;
    cn_f[e] = (float)s;
}

__global__ __launch_bounds__(256) void rvq_kernel(const float* __restrict__ z,
                                                  const float* __restrict__ cb,
                                                  const float* __restrict__ cbT,
                                                  const double* __restrict__ cn_d,
                                                  const float* __restrict__ cn_f,
                                                  int* __restrict__ idx_ws,
                                                  float* __restrict__ out) {
    __shared__ double res_d[TM][DD];                 // 32 KB fp64 master residual
    __shared__ __align__(16) float res_f[TM][DD];    // 16 KB fp32 copy for scan
    __shared__ float wmin[4][TM];
    __shared__ float minrow[TM];
    __shared__ unsigned long long wkey[4][TM];
    __shared__ int chosen[TM];

    const int tid  = threadIdx.x;
    const int lane = tid & 63;
    const int wv   = tid >> 6;
    const int row0 = blockIdx.x * TM;
    const int cbase = 4 * tid;                       // this thread's 4 codebook entries

    // load z rows -> residual (fp64 + fp32)
#pragma unroll
    for (int r = 0; r < TM; ++r) {
        float v = z[(long)(row0 + r) * DD + tid];
        res_d[r][tid] = (double)v;
        res_f[r][tid] = v;
    }
    float sq[TM];
#pragma unroll
    for (int r = 0; r < TM; ++r) sq[r] = 0.f;
    __syncthreads();

    for (int k = 0; k < KK; ++k) {
        const float*  cbk  = cb   + (long)k * CSZ * DD;
        const float*  cbTk = cbT  + (long)k * DD * CSZ;
        const float*  cnfk = cn_f + k * CSZ;
        const double* cndk = cn_d + k * CSZ;

        // ---- fp32 scan: acc[r][j] = dot(res_f[r], cb[cbase+j]) ----
        float acc[TM][4];
#pragma unroll
        for (int r = 0; r < TM; ++r)
#pragma unroll
            for (int j = 0; j < 4; ++j) acc[r][j] = 0.f;

        for (int d4 = 0; d4 < DD / 4; ++d4) {
            float cvv[4][4];                         // [dd][j]
#pragma unroll
            for (int dd = 0; dd < 4; ++dd) {
                float4 cv = *(const float4*)&cbTk[(long)(d4 * 4 + dd) * CSZ + cbase];
                cvv[dd][0] = cv.x; cvv[dd][1] = cv.y; cvv[dd][2] = cv.z; cvv[dd][3] = cv.w;
            }
#pragma unroll
            for (int r = 0; r < TM; ++r) {
                float4 rv = *(const float4*)&res_f[r][d4 * 4];   // broadcast read
#pragma unroll
                for (int j = 0; j < 4; ++j) {
                    acc[r][j] += rv.x * cvv[0][j];
                    acc[r][j] += rv.y * cvv[1][j];
                    acc[r][j] += rv.z * cvv[2][j];
                    acc[r][j] += rv.w * cvv[3][j];
                }
            }
        }

        // ---- dist = cn - 2*dot, per-thread min, block min per row ----
        float4 cn4 = *(const float4*)&cnfk[cbase];
        float cnv[4] = {cn4.x, cn4.y, cn4.z, cn4.w};
#pragma unroll
        for (int r = 0; r < TM; ++r) {
            float m = 3.4e38f;
#pragma unroll
            for (int j = 0; j < 4; ++j) {
                float dist = cnv[j] - 2.f * acc[r][j];
                acc[r][j] = dist;
                m = fminf(m, dist);
            }
#pragma unroll
            for (int off = 32; off > 0; off >>= 1)
                m = fminf(m, __shfl_down(m, off, 64));
            if (lane == 0) wmin[wv][r] = m;
        }
        __syncthreads();
        if (tid < TM)
            minrow[tid] = fminf(fminf(wmin[0][tid], wmin[1][tid]),
                                fminf(wmin[2][tid], wmin[3][tid]));
        __syncthreads();

        // ---- candidates within TAU: fp64 re-eval; wave+block min of u64 key ----
#pragma unroll
        for (int r = 0; r < TM; ++r) {
            const float thr = minrow[r] + TAU;
            unsigned long long bk = 0xFFFFFFFFFFFFFFFFull;
#pragma unroll
            for (int j = 0; j < 4; ++j) {
                if (acc[r][j] <= thr) {
                    const int c = cbase + j;
                    const float* crow = cbk + (long)c * DD;
                    double dot = 0.0;
#pragma unroll 1
                    for (int d = 0; d < DD; ++d)
                        dot += res_d[r][d] * (double)crow[d];
                    double dist = cndk[c] - 2.0 * dot;
                    unsigned long long key =
                        (enc_d(dist) & 0xFFFFFFFFFFFFFC00ull) | (unsigned long long)c;
                    bk = (key < bk) ? key : bk;
                }
            }
#pragma unroll
            for (int off = 32; off > 0; off >>= 1) {
                unsigned long long o = __shfl_down(bk, off, 64);
                bk = (o < bk) ? o : bk;
            }
            if (lane == 0) wkey[wv][r] = bk;
        }
        __syncthreads();
        if (tid < TM) {
            unsigned long long b0 = wkey[0][tid], b1 = wkey[1][tid];
            unsigned long long b2 = wkey[2][tid], b3 = wkey[3][tid];
            unsigned long long b = b0;
            b = (b1 < b) ? b1 : b;
            b = (b2 < b) ? b2 : b;
            b = (b3 < b) ? b3 : b;
            int c = (int)(b & 1023ull);
            chosen[tid] = c;
            idx_ws[(long)(row0 + tid) * KK + k] = c;     // stage to workspace (int)
        }
        __syncthreads();

        // ---- residual update (mirror reference STE arithmetic in fp64) ----
#pragma unroll
        for (int r = 0; r < TM; ++r) {
            const int c = chosen[r];
            double q  = (double)cbk[(long)c * DD + tid];
            double rd = res_d[r][tid];
            double s  = q - rd;        // stop_gradient(q - residual)
            double zq = rd + s;        // z_q value
            double rn = rd - zq;       // next residual
            res_d[r][tid] = rn;
            res_f[r][tid] = (float)rn;
            sq[r] += (float)zq;
        }
        __syncthreads();
    }

    // ---- write z_q_final as FLOAT32 (chunk 0 only) ----
#pragma unroll
    for (int r = 0; r < TM; ++r)
        out[(long)(row0 + r) * DD + tid] = sq[r];
}

// index writer: chunk 1 only, FLOAT32 values
__global__ __launch_bounds__(256) void idx_write(const int* __restrict__ idx_ws,
                                                 float* __restrict__ out) {
    int i = blockIdx.x * 256 + threadIdx.x;          // < NROWS*KK = 65536
    out[(long)NROWS * DD + i] = (float)idx_ws[i];
}

extern "C" void kernel_launch(void* const* d_in, const int* in_sizes, int n_in,
                              void* d_out, int out_size, void* d_ws, size_t ws_size,
                              hipStream_t stream) {
    (void)in_sizes; (void)n_in; (void)out_size; (void)ws_size;
    const float* z  = (const float*)d_in[0];
    const float* cb = (const float*)d_in[1];

    char* ws = (char*)d_ws;
    float*  cbT  = (float*)ws;                                  // 4 MB
    double* cn_d = (double*)(ws + (size_t)KK * CSZ * DD * 4);   // 32 KB
    float*  cn_f = (float*)(ws + (size_t)KK * CSZ * DD * 4 + (size_t)KK * CSZ * 8); // 16 KB
    int*    idxs = (int*)(ws + (size_t)KK * CSZ * DD * 4 + (size_t)KK * CSZ * 12);  // 256 KB
    float* out = (float*)d_out;

    transpose_cb<<<(KK * DD * CSZ) / 256, 256, 0, stream>>>(cb, cbT);
    cnorm_kernel<<<(KK * CSZ) / 256, 256, 0, stream>>>(cb, cn_d, cn_f);
    rvq_kernel<<<NROWS / TM, 256, 0, stream>>>(z, cb, cbT, cn_d, cn_f, idxs, out);
    idx_write<<<(NROWS * KK) / 256, 256, 0, stream>>>(idxs, out);
}

// Round 5
// 636.888 us; speedup vs baseline: 2.4954x; 2.4954x over previous
//
#include <hip/hip_runtime.h>
#include <hip/hip_bf16.h>

#define BB 8
#define TT 2048
#define DD 256
#define KK 4
#define CSZ 1024
#define NROWS (BB*TT)   // 16384
#define TM 16           // rows per block -> 1024 blocks
#define TAU 0.03f
#define MAXC 128

typedef __attribute__((ext_vector_type(8))) short bf16x8;
typedef __attribute__((ext_vector_type(4))) float f32x4;

__device__ __forceinline__ short f2bf(float f) {
    __hip_bfloat16 h = __float2bfloat16(f);
    return (short)__builtin_bit_cast(unsigned short, h);
}
__device__ __forceinline__ float bf2f(short s) {
    __hip_bfloat16 h = __builtin_bit_cast(__hip_bfloat16, (unsigned short)s);
    return __bfloat162float(h);
}
__device__ __forceinline__ unsigned enc32(float f) {
    unsigned u = __builtin_bit_cast(unsigned, f);
    return (u & 0x80000000u) ? ~u : (u | 0x80000000u);
}
__device__ __forceinline__ float dec32(unsigned e) {
    unsigned u = (e & 0x80000000u) ? (e ^ 0x80000000u) : ~e;
    return __builtin_bit_cast(float, u);
}
__device__ __forceinline__ unsigned long long enc_d(double d) {
    unsigned long long u = __double_as_longlong(d);
    return (u & 0x8000000000000000ull) ? ~u : (u | 0x8000000000000000ull);
}

// split codebook into bf16 hi/lo, same [k][c][d] layout
__global__ __launch_bounds__(256) void cb_split(const float* __restrict__ cb,
                                                short* __restrict__ hi,
                                                short* __restrict__ lo) {
    long e = (long)blockIdx.x * 256 + threadIdx.x;   // over K*CS*D = 1,048,576
    float v = cb[e];
    short h = f2bf(v);
    hi[e] = h;
    lo[e] = f2bf(v - bf2f(h));
}

// per-entry squared norms (fp64 master + fp32 for the scan)
__global__ __launch_bounds__(256) void cnorm_kernel(const float* __restrict__ cb,
                                                    double* __restrict__ cn_d,
                                                    float* __restrict__ cn_f) {
    int e = blockIdx.x * 256 + threadIdx.x;          // K*CS = 4096
    const float* p = cb + (long)e * DD;
    double s = 0.0;
    for (int d = 0; d < DD; ++d) { double v = (double)p[d]; s += v * v; }
    cn_d[e] = s;
    cn_f[e] = (float)s;
}

__global__ __launch_bounds__(256) void rvq_kernel(const float* __restrict__ z,
                                                  const float* __restrict__ cb,
                                                  const short* __restrict__ cb_hi,
                                                  const short* __restrict__ cb_lo,
                                                  const double* __restrict__ cn_d,
                                                  const float* __restrict__ cn_f,
                                                  int* __restrict__ idx_ws,
                                                  float* __restrict__ out) {
    __shared__ double res_d[TM][DD + 1];                  // fp64 master, padded
    __shared__ __align__(16) short res_h[TM][DD + 8];     // bf16 hi, padded to 16B
    __shared__ __align__(16) short res_l[TM][DD + 8];     // bf16 lo
    __shared__ unsigned wrowmin[4][TM];
    __shared__ unsigned rowmin[TM];
    __shared__ int cand[MAXC];
    __shared__ unsigned long long cres[MAXC];
    __shared__ int chosen[TM];
    __shared__ int ncand;

    const int tid = threadIdx.x;
    const int l   = tid & 63;        // lane
    const int wv  = tid >> 6;        // wave 0..3
    const int l15 = l & 15;
    const int q   = l >> 4;          // quarter 0..3
    const int q8  = q * 8;
    const int row0 = blockIdx.x * TM;

    // ---- init: z -> residual (fp64 master + bf16 hi/lo) ----
    float sq[TM];
#pragma unroll
    for (int r = 0; r < TM; ++r) {
        float v = z[(size_t)(row0 + r) * DD + tid];
        res_d[r][tid] = (double)v;
        short h = f2bf(v);
        res_h[r][tid] = h;
        res_l[r][tid] = f2bf(v - bf2f(h));
        sq[r] = 0.f;
    }

    for (int k = 0; k < KK; ++k) {
        if (tid == 0) ncand = 0;
        __syncthreads();                                  // residual ready

        // ---- A fragments (row = l15, d = kk*32 + q8 + j) ----
        bf16x8 Ah[8], Al[8];
#pragma unroll
        for (int kk = 0; kk < 8; ++kk) {
            Ah[kk] = *(const bf16x8*)&res_h[l15][kk * 32 + q8];
            Al[kk] = *(const bf16x8*)&res_l[l15][kk * 32 + q8];
        }

        // ---- MFMA scan over this wave's 256 entries (16 tiles of 16) ----
        const short* __restrict__ cbhk = cb_hi + (size_t)k * CSZ * DD;
        const short* __restrict__ cblk = cb_lo + (size_t)k * CSZ * DD;
        const float* __restrict__ cnfk = cn_f + k * CSZ;
        unsigned b0[4] = {~0u, ~0u, ~0u, ~0u};            // best key per row-slot
        unsigned b1[4] = {~0u, ~0u, ~0u, ~0u};            // 2nd best
        const int seg = wv * 256;
        for (int ct = 0; ct < 16; ++ct) {
            const int cE = seg + ct * 16 + l15;           // this lane's entry (B col)
            const short* bh = cbhk + (size_t)cE * DD + q8;
            const short* bl = cblk + (size_t)cE * DD + q8;
            bf16x8 Bh[8], Bl[8];
#pragma unroll
            for (int kk = 0; kk < 8; ++kk) {
                Bh[kk] = *(const bf16x8*)(bh + kk * 32);
                Bl[kk] = *(const bf16x8*)(bl + kk * 32);
            }
            f32x4 acc = {0.f, 0.f, 0.f, 0.f};
#pragma unroll
            for (int kk = 0; kk < 8; ++kk) {
                acc = __builtin_amdgcn_mfma_f32_16x16x32_bf16(Ah[kk], Bh[kk], acc, 0, 0, 0);
                acc = __builtin_amdgcn_mfma_f32_16x16x32_bf16(Ah[kk], Bl[kk], acc, 0, 0, 0);
                acc = __builtin_amdgcn_mfma_f32_16x16x32_bf16(Al[kk], Bh[kk], acc, 0, 0, 0);
            }
            float cn = cnfk[cE];
#pragma unroll
            for (int reg = 0; reg < 4; ++reg) {           // C row = q*4+reg, col = l15
                float dist = fmaf(-2.f, acc[reg], cn);
                unsigned key = (enc32(dist) & 0xFFFFFC00u) | (unsigned)cE;
                unsigned mx = (b0[reg] > key) ? b0[reg] : key;
                b0[reg] = (b0[reg] < key) ? b0[reg] : key;
                b1[reg] = (b1[reg] < mx) ? b1[reg] : mx;
            }
        }

        // ---- per-wave row min (reduce over 16 lanes of each quarter) ----
#pragma unroll
        for (int reg = 0; reg < 4; ++reg) {
            unsigned m = b0[reg];
            m = min(m, (unsigned)__shfl_xor((int)m, 1, 64));
            m = min(m, (unsigned)__shfl_xor((int)m, 2, 64));
            m = min(m, (unsigned)__shfl_xor((int)m, 4, 64));
            m = min(m, (unsigned)__shfl_xor((int)m, 8, 64));
            if (l15 == 0) wrowmin[wv][q * 4 + reg] = m;
        }
        __syncthreads();
        if (tid < TM)
            rowmin[tid] = min(min(wrowmin[0][tid], wrowmin[1][tid]),
                              min(wrowmin[2][tid], wrowmin[3][tid]));
        __syncthreads();

        // ---- candidate capture: keys within TAU of row min ----
#pragma unroll
        for (int reg = 0; reg < 4; ++reg) {
            const int row = q * 4 + reg;
            unsigned rk = rowmin[row];
            float thrf = dec32(rk | 0x3FFu) + TAU;
            unsigned tkey = (enc32(thrf) & 0xFFFFFC00u) | 0x3FFu;
            if (b0[reg] <= tkey) {
                int s = atomicAdd(&ncand, 1);
                if (s < MAXC) cand[s] = row | ((int)(b0[reg] & 0x3FFu) << 16);
            }
            if (b1[reg] <= tkey) {
                int s = atomicAdd(&ncand, 1);
                if (s < MAXC) cand[s] = row | ((int)(b1[reg] & 0x3FFu) << 16);
            }
        }
        __syncthreads();

        // ---- fp64 refine: one candidate per wave iteration, 64-lane dot ----
        const int nc = (ncand < MAXC) ? ncand : MAXC;
        const float* __restrict__ cbk  = cb + (size_t)k * CSZ * DD;
        const double* __restrict__ cndk = cn_d + k * CSZ;
        for (int i = wv; i < nc; i += 4) {
            int rc = cand[i];
            int row = rc & 0xFFFF;
            int c   = rc >> 16;
            const float* crow = cbk + (size_t)c * DD;
            double p = 0.0;
#pragma unroll
            for (int j = 0; j < 4; ++j)
                p += res_d[row][4 * l + j] * (double)crow[4 * l + j];
#pragma unroll
            for (int off = 32; off > 0; off >>= 1)
                p += __shfl_xor(p, off, 64);
            if (l == 0) {
                double dist = cndk[c] - 2.0 * p;
                cres[i] = (enc_d(dist) & 0xFFFFFFFFFFFFFC00ull) | (unsigned long long)c;
            }
        }
        __syncthreads();

        // ---- select per row (first-index tie-break via key) ----
        if (tid < TM) {
            unsigned long long best = ~0ull;
            for (int i = 0; i < nc; ++i)
                if ((cand[i] & 0xFFFF) == tid) {
                    unsigned long long v = cres[i];
                    best = (v < best) ? v : best;
                }
            int c = (int)(best & 1023ull);
            chosen[tid] = c;
            idx_ws[(size_t)(row0 + tid) * KK + k] = c;
        }
        __syncthreads();

        // ---- residual update (fp64 mirror of reference STE) ----
#pragma unroll
        for (int r = 0; r < TM; ++r) {
            int c = chosen[r];
            double qv = (double)cbk[(size_t)c * DD + tid];
            double rd = res_d[r][tid];
            double s  = qv - rd;       // stop_gradient(q - residual)
            double zq = rd + s;        // z_q value
            double rn = rd - zq;       // next residual
            res_d[r][tid] = rn;
            float rf = (float)rn;
            short h = f2bf(rf);
            res_h[r][tid] = h;
            res_l[r][tid] = f2bf(rf - bf2f(h));
            sq[r] += (float)zq;
        }
        __syncthreads();
    }

    // ---- write z_q_final as float32 (chunk 0) ----
#pragma unroll
    for (int r = 0; r < TM; ++r)
        out[(size_t)(row0 + r) * DD + tid] = sq[r];
}

// index writer: chunk 1, float32 values
__global__ __launch_bounds__(256) void idx_write(const int* __restrict__ idx_ws,
                                                 float* __restrict__ out) {
    int i = blockIdx.x * 256 + threadIdx.x;          // < NROWS*KK = 65536
    out[(long)NROWS * DD + i] = (float)idx_ws[i];
}

extern "C" void kernel_launch(void* const* d_in, const int* in_sizes, int n_in,
                              void* d_out, int out_size, void* d_ws, size_t ws_size,
                              hipStream_t stream) {
    (void)in_sizes; (void)n_in; (void)out_size; (void)ws_size;
    const float* z  = (const float*)d_in[0];
    const float* cb = (const float*)d_in[1];

    char* ws = (char*)d_ws;
    short*  cb_hi = (short*)ws;                                   // 2 MB
    short*  cb_lo = (short*)(ws + (size_t)2 * 1024 * 1024);       // 2 MB
    double* cn_d  = (double*)(ws + (size_t)4 * 1024 * 1024);      // 32 KB
    float*  cn_f  = (float*)(ws + (size_t)4 * 1024 * 1024 + 32 * 1024);  // 16 KB
    int*    idxs  = (int*)(ws + (size_t)4 * 1024 * 1024 + 48 * 1024);    // 256 KB
    float* out = (float*)d_out;

    cb_split<<<(KK * CSZ * DD) / 256, 256, 0, stream>>>(cb, cb_hi, cb_lo);
    cnorm_kernel<<<(KK * CSZ) / 256, 256, 0, stream>>>(cb, cn_d, cn_f);
    rvq_kernel<<<NROWS / TM, 256, 0, stream>>>(z, cb, cb_hi, cb_lo, cn_d, cn_f, idxs, out);
    idx_write<<<(NROWS * KK) / 256, 256, 0, stream>>>(idxs, out);
}

// Round 7
// 285.515 us; speedup vs baseline: 5.5663x; 2.2307x over previous
//
#include <hip/hip_runtime.h>
#include <hip/hip_bf16.h>

#define BATB 8
#define TT 2048
#define DD 256
#define KK 4
#define CSZ 1024
#define NROWS (BATB*TT) // 16384
#define TM 32           // rows per block -> 512 blocks
#define TAU 0.5f
#define MAXC 256

typedef __attribute__((ext_vector_type(8))) short bf16x8;
typedef __attribute__((ext_vector_type(4))) float f32x4;

__device__ __forceinline__ short f2bf(float f) {
    __hip_bfloat16 h = __float2bfloat16(f);
    return (short)__builtin_bit_cast(unsigned short, h);
}
__device__ __forceinline__ unsigned enc32(float f) {
    unsigned u = __builtin_bit_cast(unsigned, f);
    return (u & 0x80000000u) ? ~u : (u | 0x80000000u);
}
__device__ __forceinline__ float dec32(unsigned e) {
    unsigned u = (e & 0x80000000u) ? (e ^ 0x80000000u) : ~e;
    return __builtin_bit_cast(float, u);
}
__device__ __forceinline__ unsigned long long enc_d(double d) {
    unsigned long long u = __double_as_longlong(d);
    return (u & 0x8000000000000000ull) ? ~u : (u | 0x8000000000000000ull);
}

// bf16 (hi) copy of codebook, same [k][c][d] layout
__global__ __launch_bounds__(256) void cb_tobf(const float* __restrict__ cb,
                                               short* __restrict__ hi) {
    long e = (long)blockIdx.x * 256 + threadIdx.x;   // over K*CS*D = 1,048,576
    hi[e] = f2bf(cb[e]);
}

// per-entry squared norms (fp64 master + fp32 for the scan)
__global__ __launch_bounds__(256) void cnorm_kernel(const float* __restrict__ cb,
                                                    double* __restrict__ cn_d,
                                                    float* __restrict__ cn_f) {
    int e = blockIdx.x * 256 + threadIdx.x;          // K*CS = 4096
    const float* p = cb + (long)e * DD;
    double s = 0.0;
    for (int d = 0; d < DD; ++d) { double v = (double)p[d]; s += v * v; }
    cn_d[e] = s;
    cn_f[e] = (float)s;
}

#define LOADB(Bv, CNv, ct_) {                                         \
    const int cE_ = seg + (ct_) * 16 + l15;                           \
    const short* bp_ = cbhk + (size_t)cE_ * DD + q8;                  \
    _Pragma("unroll")                                                 \
    for (int kk = 0; kk < 8; ++kk)                                    \
        Bv[kk] = *(const bf16x8*)(bp_ + kk * 32);                     \
    CNv = cnfk[cE_]; }

#define TILE(Bv, CNv, ct_) {                                          \
    f32x4 a0 = {0.f,0.f,0.f,0.f}, a1 = {0.f,0.f,0.f,0.f};             \
    _Pragma("unroll")                                                 \
    for (int kk = 0; kk < 8; ++kk) {                                  \
        a0 = __builtin_amdgcn_mfma_f32_16x16x32_bf16(A0[kk], Bv[kk], a0, 0,0,0); \
        a1 = __builtin_amdgcn_mfma_f32_16x16x32_bf16(A1[kk], Bv[kk], a1, 0,0,0); \
    }                                                                 \
    const int cE_ = seg + (ct_) * 16 + l15;                           \
    _Pragma("unroll")                                                 \
    for (int reg = 0; reg < 4; ++reg) {                               \
        float d0_ = fmaf(-2.f, a0[reg], CNv);                         \
        unsigned k0_ = (enc32(d0_) & 0xFFFFFC00u) | (unsigned)cE_;    \
        unsigned m0_ = (bA0[reg] > k0_) ? bA0[reg] : k0_;             \
        bA0[reg] = (bA0[reg] < k0_) ? bA0[reg] : k0_;                 \
        bA1[reg] = (bA1[reg] < m0_) ? bA1[reg] : m0_;                 \
        float d1_ = fmaf(-2.f, a1[reg], CNv);                         \
        unsigned k1_ = (enc32(d1_) & 0xFFFFFC00u) | (unsigned)cE_;    \
        unsigned m1_ = (bB0[reg] > k1_) ? bB0[reg] : k1_;             \
        bB0[reg] = (bB0[reg] < k1_) ? bB0[reg] : k1_;                 \
        bB1[reg] = (bB1[reg] < m1_) ? bB1[reg] : m1_;                 \
    } }

__global__ __launch_bounds__(256) void rvq_kernel(const float* __restrict__ z,
                                                  const float* __restrict__ cb,
                                                  const short* __restrict__ cb_hi,
                                                  const double* __restrict__ cn_d,
                                                  const float* __restrict__ cn_f,
                                                  int* __restrict__ idx_ws,
                                                  float* __restrict__ out) {
    __shared__ double res_d[TM][DD + 2];             // 66 KB fp64 master residual
    __shared__ unsigned wrowmin[4][TM];
    __shared__ unsigned rowmin[TM];
    __shared__ int cand[MAXC];
    __shared__ unsigned long long cres[MAXC];
    __shared__ int chosen[TM];
    __shared__ int ncand;

    const int tid = threadIdx.x;
    const int l   = tid & 63;        // lane
    const int wv  = tid >> 6;        // wave 0..3
    const int l15 = l & 15;
    const int q   = l >> 4;          // quarter 0..3
    const int q8  = q * 8;
    const int row0 = blockIdx.x * TM;
    const int seg  = wv * 256;       // this wave's codebook segment

    // ---- init: z -> fp64 residual ----
#pragma unroll
    for (int r = 0; r < TM; ++r)
        res_d[r][tid] = (double)z[(size_t)(row0 + r) * DD + tid];
    __syncthreads();

    for (int k = 0; k < KK; ++k) {
        // ---- A fragments from fp64 residual: rt0 = row l15, rt1 = row 16+l15 ----
        bf16x8 A0[8], A1[8];
#pragma unroll
        for (int kk = 0; kk < 8; ++kk) {
            const double* r0 = &res_d[l15][kk * 32 + q8];
            const double* r1 = &res_d[16 + l15][kk * 32 + q8];
#pragma unroll
            for (int j = 0; j < 8; ++j) {
                A0[kk][j] = f2bf((float)r0[j]);
                A1[kk][j] = f2bf((float)r1[j]);
            }
        }

        // ---- MFMA scan over this wave's 256 entries, double-buffered ----
        const short* __restrict__ cbhk = cb_hi + (size_t)k * CSZ * DD;
        const float* __restrict__ cnfk = cn_f + k * CSZ;
        unsigned bA0[4] = {~0u,~0u,~0u,~0u}, bA1[4] = {~0u,~0u,~0u,~0u};
        unsigned bB0[4] = {~0u,~0u,~0u,~0u}, bB1[4] = {~0u,~0u,~0u,~0u};

        bf16x8 Bp[8], Bq[8];
        float cnP, cnQ;
        LOADB(Bp, cnP, 0);
        for (int ct2 = 0; ct2 < 8; ++ct2) {
            LOADB(Bq, cnQ, 2 * ct2 + 1);
            TILE(Bp, cnP, 2 * ct2);
            if (ct2 < 7) LOADB(Bp, cnP, 2 * ct2 + 2);
            TILE(Bq, cnQ, 2 * ct2 + 1);
        }

        // ---- per-wave row min (reduce over 16 lanes of each quarter) ----
#pragma unroll
        for (int reg = 0; reg < 4; ++reg) {
            unsigned m = bA0[reg];
            m = min(m, (unsigned)__shfl_xor((int)m, 1, 64));
            m = min(m, (unsigned)__shfl_xor((int)m, 2, 64));
            m = min(m, (unsigned)__shfl_xor((int)m, 4, 64));
            m = min(m, (unsigned)__shfl_xor((int)m, 8, 64));
            if (l15 == 0) wrowmin[wv][q * 4 + reg] = m;
            unsigned n = bB0[reg];
            n = min(n, (unsigned)__shfl_xor((int)n, 1, 64));
            n = min(n, (unsigned)__shfl_xor((int)n, 2, 64));
            n = min(n, (unsigned)__shfl_xor((int)n, 4, 64));
            n = min(n, (unsigned)__shfl_xor((int)n, 8, 64));
            if (l15 == 0) wrowmin[wv][16 + q * 4 + reg] = n;
        }
        __syncthreads();
        if (tid < TM)
            rowmin[tid] = min(min(wrowmin[0][tid], wrowmin[1][tid]),
                              min(wrowmin[2][tid], wrowmin[3][tid]));
        if (tid == 0) ncand = 0;
        __syncthreads();

        // ---- candidate capture: best + 2nd-best per lane-slot within TAU ----
#pragma unroll
        for (int s = 0; s < 8; ++s) {
            const int rt  = s >> 2;
            const int reg = s & 3;
            const int row = rt * 16 + q * 4 + reg;
            unsigned rk = rowmin[row];
            float thrf = dec32(rk | 0x3FFu) + TAU;
            unsigned tkey = (enc32(thrf) & 0xFFFFFC00u) | 0x3FFu;
            unsigned v0 = rt ? bB0[reg] : bA0[reg];
            unsigned v1 = rt ? bB1[reg] : bA1[reg];
            if (v0 <= tkey) {
                int sl = atomicAdd(&ncand, 1);
                if (sl < MAXC) cand[sl] = row | ((int)(v0 & 0x3FFu) << 16);
            }
            if (v1 <= tkey) {
                int sl = atomicAdd(&ncand, 1);
                if (sl < MAXC) cand[sl] = row | ((int)(v1 & 0x3FFu) << 16);
            }
        }
        __syncthreads();

        // ---- fp64 refine: one candidate per wave iteration, 64-lane dot ----
        const int nc = (ncand < MAXC) ? ncand : MAXC;
        const float* __restrict__ cbk  = cb + (size_t)k * CSZ * DD;
        const double* __restrict__ cndk = cn_d + k * CSZ;
        for (int i = wv; i < nc; i += 4) {
            int rc  = cand[i];
            int row = rc & 0xFFFF;
            int c   = rc >> 16;
            const float* crow = cbk + (size_t)c * DD;
            double p = 0.0;
#pragma unroll
            for (int j = 0; j < 4; ++j)
                p += res_d[row][4 * l + j] * (double)crow[4 * l + j];
#pragma unroll
            for (int off = 32; off > 0; off >>= 1)
                p += __shfl_xor(p, off, 64);
            if (l == 0) {
                double dist = cndk[c] - 2.0 * p;
                cres[i] = (enc_d(dist) & 0xFFFFFFFFFFFFFC00ull) | (unsigned long long)c;
            }
        }
        __syncthreads();

        // ---- select per row (first-index tie-break via truncated key) ----
        if (tid < TM) {
            unsigned long long best = ~0ull;
            for (int i = 0; i < nc; ++i)
                if ((cand[i] & 0xFFFF) == tid) {
                    unsigned long long v = cres[i];
                    best = (v < best) ? v : best;
                }
            int c = (int)(best & 1023ull);
            chosen[tid] = c;
            idx_ws[(size_t)(row0 + tid) * KK + k] = c;
        }
        __syncthreads();

        // ---- residual update (fp64 mirror of reference STE) ----
#pragma unroll
        for (int r = 0; r < TM; ++r) {
            int c = chosen[r];
            double qv = (double)cbk[(size_t)c * DD + tid];
            double rd = res_d[r][tid];
            double s  = qv - rd;       // stop_gradient(q - residual)
            double zq = rd + s;        // z_q value
            res_d[r][tid] = rd - zq;   // next residual
        }
        __syncthreads();
    }

    // ---- z_q_final = z - residual_final (f32 out, chunk 0) ----
#pragma unroll
    for (int r = 0; r < TM; ++r) {
        size_t o = (size_t)(row0 + r) * DD + tid;
        out[o] = (float)((double)z[o] - res_d[r][tid]);
    }
}

// index writer: chunk 1, float32 values
__global__ __launch_bounds__(256) void idx_write(const int* __restrict__ idx_ws,
                                                 float* __restrict__ out) {
    int i = blockIdx.x * 256 + threadIdx.x;          // < NROWS*KK = 65536
    out[(long)NROWS * DD + i] = (float)idx_ws[i];
}

extern "C" void kernel_launch(void* const* d_in, const int* in_sizes, int n_in,
                              void* d_out, int out_size, void* d_ws, size_t ws_size,
                              hipStream_t stream) {
    (void)in_sizes; (void)n_in; (void)out_size; (void)ws_size;
    const float* z  = (const float*)d_in[0];
    const float* cb = (const float*)d_in[1];

    char* ws = (char*)d_ws;
    short*  cb_hi = (short*)ws;                                   // 2 MB
    double* cn_d  = (double*)(ws + (size_t)2 * 1024 * 1024);      // 32 KB
    float*  cn_f  = (float*)(ws + (size_t)2 * 1024 * 1024 + 32 * 1024);  // 16 KB
    int*    idxs  = (int*)(ws + (size_t)2 * 1024 * 1024 + 48 * 1024);    // 256 KB
    float* out = (float*)d_out;

    cb_tobf<<<(KK * CSZ * DD) / 256, 256, 0, stream>>>(cb, cb_hi);
    cnorm_kernel<<<(KK * CSZ) / 256, 256, 0, stream>>>(cb, cn_d, cn_f);
    rvq_kernel<<<NROWS / TM, 256, 0, stream>>>(z, cb, cb_hi, cn_d, cn_f, idxs, out);
    idx_write<<<(NROWS * KK) / 256, 256, 0, stream>>>(idxs, out);
}